// Round 15
// baseline (164.061 us; speedup 1.0000x reference)
//
#include <hip/hip_runtime.h>
#include <hip/hip_bf16.h>

#define IN_CH 48
#define OUT_CH 48
#define BN_EPS 1e-5f
#define CHUNK 4096          // edges per bin block
#define EPT   16            // edges per thread in bin role (CHUNK/256)
#define NPB   256           // nodes per bucket (bucket = dst >> 8)
#define NHB   512           // histogram blocks

__device__ __forceinline__ float bf2f(ushort u) {
    union { unsigned int i; float f; } v;
    v.i = ((unsigned int)u) << 16;
    return v.f;
}
__device__ __forceinline__ ushort f2bf(float f) {
    __hip_bfloat16 h = __float2bfloat16(f);  // round-to-nearest-even
    return *(ushort*)&h;
}

// ---------------------------------------------------------------------------
// k_zero: bhist[512] = 0 (1 block)
// ---------------------------------------------------------------------------
__global__ __launch_bounds__(512) void k_zero(int* __restrict__ bhist) {
    bhist[threadIdx.x] = 0;
}

// ---------------------------------------------------------------------------
// k_binhist: 512 blocks, LDS bucket hist, global-atomic flush, unroll-4.
// ---------------------------------------------------------------------------
__global__ __launch_bounds__(256) void k_binhist(const int* __restrict__ dst,
                                                 int* __restrict__ bhist, int E) {
    __shared__ int h[512];
    int t = threadIdx.x;
    h[t] = 0; h[t + 256] = 0;
    __syncthreads();
    const int stride = NHB * 256;
    int e = blockIdx.x * 256 + t;
    for (; e + 3 * stride < E; e += 4 * stride) {
        int d0 = dst[e];
        int d1 = dst[e + stride];
        int d2 = dst[e + 2 * stride];
        int d3 = dst[e + 3 * stride];
        atomicAdd(&h[d0 >> 8], 1);
        atomicAdd(&h[d1 >> 8], 1);
        atomicAdd(&h[d2 >> 8], 1);
        atomicAdd(&h[d3 >> 8], 1);
    }
    for (; e < E; e += stride) atomicAdd(&h[dst[e] >> 8], 1);
    __syncthreads();
    if (h[t]) atomicAdd(&bhist[t], h[t]);
    if (h[t + 256]) atomicAdd(&bhist[t + 256], h[t + 256]);
}

// ---------------------------------------------------------------------------
// k_scanb: exclusive scan of bhist -> bstart, bcur. Zeroes stats[128].
// ---------------------------------------------------------------------------
__global__ __launch_bounds__(256) void k_scanb(const int* __restrict__ bhist,
                                               int* __restrict__ bstart,
                                               int* __restrict__ bcur, int nb,
                                               float* __restrict__ stats) {
    __shared__ int sc[256];
    int t = threadIdx.x;
    if (t < 128) stats[t] = 0.0f;
    int i0 = 2 * t, i1 = 2 * t + 1;
    int a0 = bhist[i0];
    int a1 = bhist[i1];
    int ps = a0 + a1;
    sc[t] = ps;
    __syncthreads();
    for (int off = 1; off < 256; off <<= 1) {
        int v = (t >= off) ? sc[t - off] : 0;
        __syncthreads();
        sc[t] += v;
        __syncthreads();
    }
    int excl = sc[t] - ps;
    bstart[i0] = excl;
    bstart[i1] = excl + a0;
    if (i0 < nb) bcur[i0] = excl;
    if (i1 < nb) bcur[i1] = excl + a0;
    if (t == 255) bstart[512] = sc[255];  // == E
}

// ---------------------------------------------------------------------------
// k_binmm: role-split fusion. Bin blocks sort a 4096-edge chunk; gemm blocks
// compute UNSCALED g = bf16(x@W) in COLUMN-BLOCKED layout [3][N][16ch]
// (32B row-parts so each gather pass's working set fits one XCD's 4MB L2).
// ---------------------------------------------------------------------------
union alignas(16) SMem {
    struct {
        int hist[512];
        int hbase[513];
        int sc[256];
        int gb[512];
        unsigned int stage[CHUNK];
        short stagebk[CHUNK];
    } bin;
    float Wl[IN_CH * OUT_CH];
};

__global__ __launch_bounds__(256) void k_binmm(const int* __restrict__ src,
                                               const int* __restrict__ dst,
                                               int* __restrict__ bcur,
                                               unsigned int* __restrict__ binned,
                                               int E, int nchunks,
                                               const float* __restrict__ x,
                                               const float* __restrict__ W,
                                               ushort* __restrict__ g, int N) {
    __shared__ SMem sm;
    int t = threadIdx.x;

    if (blockIdx.x < nchunks) {
        // ------------------- bin role -------------------
        int e0 = blockIdx.x * CHUNK;
        int n = min(CHUNK, E - e0);

        sm.bin.hist[t] = 0; sm.bin.hist[t + 256] = 0;
        __syncthreads();

        unsigned int w[EPT];
        short bb[EPT];
#pragma unroll
        for (int k = 0; k < EPT; ++k) {
            int i = t + k * 256;
            if (i < n) {
                int e = e0 + i;
                int s = src[e], d = dst[e];
                int b = d >> 8;
                w[k] = (unsigned int)s | ((unsigned int)(d & 255) << 17);
                bb[k] = (short)b;
                atomicAdd(&sm.bin.hist[b], 1);
            } else bb[k] = -1;
        }
        __syncthreads();
        int a0 = sm.bin.hist[2 * t], a1 = sm.bin.hist[2 * t + 1];
        int ps = a0 + a1;
        sm.bin.sc[t] = ps;
        __syncthreads();
        for (int off = 1; off < 256; off <<= 1) {
            int v = (t >= off) ? sm.bin.sc[t - off] : 0;
            __syncthreads();
            sm.bin.sc[t] += v;
            __syncthreads();
        }
        int excl = sm.bin.sc[t] - ps;
        sm.bin.hbase[2 * t] = excl;
        sm.bin.hbase[2 * t + 1] = excl + a0;
        if (t == 255) sm.bin.hbase[512] = sm.bin.sc[255];  // == n
        __syncthreads();
        sm.bin.hist[2 * t] = excl;            // cursors
        sm.bin.hist[2 * t + 1] = excl + a0;
        __syncthreads();
#pragma unroll
        for (int k = 0; k < EPT; ++k) {
            if (bb[k] >= 0) {
                int pos = atomicAdd(&sm.bin.hist[bb[k]], 1);
                sm.bin.stage[pos] = w[k];
                sm.bin.stagebk[pos] = bb[k];
            }
        }
        __syncthreads();
        for (int b = t; b < 512; b += 256) {
            int cnt = sm.bin.hbase[b + 1] - sm.bin.hbase[b];
            if (cnt > 0) sm.bin.gb[b] = atomicAdd(&bcur[b], cnt) - sm.bin.hbase[b];
        }
        __syncthreads();
        for (int j = t; j < n; j += 256) {
            int bk = sm.bin.stagebk[j];
            binned[sm.bin.gb[bk] + j] = sm.bin.stage[j];
        }
    } else {
        // ------------------- gemm role (unscaled, column-blocked) ----------
        for (int idx = t; idx < IN_CH * OUT_CH / 4; idx += 256)
            ((float4*)sm.Wl)[idx] = ((const float4*)W)[idx];
        __syncthreads();

        int i = (blockIdx.x - nchunks) * 256 + t;
        if (i >= N) return;

        float xr[IN_CH];
        const float4* xp = (const float4*)(x + (size_t)i * IN_CH);
#pragma unroll
        for (int k = 0; k < IN_CH / 4; ++k) {
            float4 v = xp[k];
            xr[4 * k] = v.x; xr[4 * k + 1] = v.y; xr[4 * k + 2] = v.z; xr[4 * k + 3] = v.w;
        }

        ushort row[OUT_CH];
#pragma unroll
        for (int c4 = 0; c4 < OUT_CH / 4; ++c4) {
            float4 acc = make_float4(0.f, 0.f, 0.f, 0.f);
#pragma unroll
            for (int k = 0; k < IN_CH; ++k) {
                float4 wv = ((const float4*)sm.Wl)[k * (OUT_CH / 4) + c4];
                acc.x += xr[k] * wv.x; acc.y += xr[k] * wv.y;
                acc.z += xr[k] * wv.z; acc.w += xr[k] * wv.w;
            }
            row[4 * c4 + 0] = f2bf(acc.x);
            row[4 * c4 + 1] = f2bf(acc.y);
            row[4 * c4 + 2] = f2bf(acc.z);
            row[4 * c4 + 3] = f2bf(acc.w);
        }
        // column-blocked store: part p holds channels [16p, 16p+16)
#pragma unroll
        for (int p = 0; p < 3; ++p) {
            uint4* gp = (uint4*)(g + ((size_t)p * N + i) * 16);
            gp[0] = ((uint4*)row)[2 * p];
            gp[1] = ((uint4*)row)[2 * p + 1];
        }
    }
}

// ---------------------------------------------------------------------------
// k_fine: one block per bucket. LDS hist over binned -> counts + rowstart,
// scatter src ids into the bucket's contiguous window, then RESCALE the
// bucket's g row-parts by dinv (column-blocked layout).
// ---------------------------------------------------------------------------
__global__ __launch_bounds__(512) void k_fine(const unsigned int* __restrict__ binned,
                                              const int* __restrict__ bstart,
                                              int* __restrict__ counts,
                                              int* __restrict__ rowstart,
                                              int* __restrict__ sorted_src,
                                              ushort* __restrict__ g, int N) {
    __shared__ int cnt[256];
    __shared__ int sc[256];
    __shared__ int cur[256];
    __shared__ float sdinv[256];
    int b = blockIdx.x, t = threadIdx.x;
    int node0 = b << 8;
    int nn = min(NPB, N - node0);
    if (t < 256) cnt[t] = 0;
    __syncthreads();
    int e0 = bstart[b], e1 = bstart[b + 1];
    for (int e = e0 + t; e < e1; e += 512)
        atomicAdd(&cnt[binned[e] >> 17], 1);
    __syncthreads();
    if (t < 256) sc[t] = cnt[t];
    __syncthreads();
    for (int off = 1; off < 256; off <<= 1) {
        int v = 0;
        if (t < 256 && t >= off) v = sc[t - off];
        __syncthreads();
        if (t < 256) sc[t] += v;
        __syncthreads();
    }
    if (t < 256) {
        int excl = sc[t] - cnt[t];
        cur[t] = e0 + excl;
        sdinv[t] = rsqrtf((float)cnt[t] + 1.0f);
        if (t < nn) {
            counts[node0 + t] = cnt[t];
            rowstart[node0 + t] = e0 + excl;
        }
    }
    __syncthreads();
    for (int e = e0 + t; e < e1; e += 512) {
        unsigned int w = binned[e];
        int dl = (int)(w >> 17);
        int pos = atomicAdd(&cur[dl], 1);
        sorted_src[pos] = (int)(w & 0x1ffff);
    }
    // rescale this bucket's g row-parts: g[p][node] *= dinv[node]
    for (int p = 0; p < 3; ++p) {
        unsigned int* gw = (unsigned int*)(g + ((size_t)p * N + node0) * 16);
        int words = nn * 8;  // 8 uint words per 16-ch row-part
        for (int i = t; i < words; i += 512) {
            int r = i >> 3;
            float d = sdinv[r];
            unsigned int u = gw[i];
            float lo = bf2f((ushort)(u & 0xffff)) * d;
            float hi = bf2f((ushort)(u >> 16)) * d;
            gw[i] = (unsigned int)f2bf(lo) | ((unsigned int)f2bf(hi) << 16);
        }
    }
}

// ---------------------------------------------------------------------------
// k_gather3: ONE column block (16 channels, 3.2MB working set -> fits one
// XCD's 4MB L2). Thread per (node, 4-ch lane); uint2 loads, unroll-8.
// sorted_src loads + out stores are NON-TEMPORAL so streams don't evict g.
// ---------------------------------------------------------------------------
__global__ __launch_bounds__(256) void k_gather3(const int* __restrict__ sorted_src,
                                                 const int* __restrict__ rowstart,
                                                 const int* __restrict__ counts,
                                                 const ushort* __restrict__ g,
                                                 float* __restrict__ out,
                                                 int N, int part) {
    int t = blockIdx.x * blockDim.x + threadIdx.x;
    if (t >= N * 4) return;
    int node = t >> 2;
    int sub = t & 3;                   // 4 ch of this part: [4*sub, 4*sub+4)
    const uint2* gp = (const uint2*)(g + ((size_t)part * N) * 16);  // part base
    int cnt = counts[node];
    int e = rowstart[node];
    int end = e + cnt;

    uint2 sv = gp[(size_t)node * 4 + sub];  // self loop
    float a0 = bf2f((ushort)(sv.x & 0xffff));
    float a1 = bf2f((ushort)(sv.x >> 16));
    float a2 = bf2f((ushort)(sv.y & 0xffff));
    float a3 = bf2f((ushort)(sv.y >> 16));

    for (; e + 8 <= end; e += 8) {
        int s0 = __builtin_nontemporal_load(&sorted_src[e]);
        int s1 = __builtin_nontemporal_load(&sorted_src[e + 1]);
        int s2 = __builtin_nontemporal_load(&sorted_src[e + 2]);
        int s3 = __builtin_nontemporal_load(&sorted_src[e + 3]);
        int s4 = __builtin_nontemporal_load(&sorted_src[e + 4]);
        int s5 = __builtin_nontemporal_load(&sorted_src[e + 5]);
        int s6 = __builtin_nontemporal_load(&sorted_src[e + 6]);
        int s7 = __builtin_nontemporal_load(&sorted_src[e + 7]);
        uint2 v0 = gp[(size_t)s0 * 4 + sub];
        uint2 v1 = gp[(size_t)s1 * 4 + sub];
        uint2 v2 = gp[(size_t)s2 * 4 + sub];
        uint2 v3 = gp[(size_t)s3 * 4 + sub];
        uint2 v4 = gp[(size_t)s4 * 4 + sub];
        uint2 v5 = gp[(size_t)s5 * 4 + sub];
        uint2 v6 = gp[(size_t)s6 * 4 + sub];
        uint2 v7 = gp[(size_t)s7 * 4 + sub];
        a0 += (bf2f((ushort)(v0.x & 0xffff)) + bf2f((ushort)(v1.x & 0xffff)))
            + (bf2f((ushort)(v2.x & 0xffff)) + bf2f((ushort)(v3.x & 0xffff)))
            + (bf2f((ushort)(v4.x & 0xffff)) + bf2f((ushort)(v5.x & 0xffff)))
            + (bf2f((ushort)(v6.x & 0xffff)) + bf2f((ushort)(v7.x & 0xffff)));
        a1 += (bf2f((ushort)(v0.x >> 16)) + bf2f((ushort)(v1.x >> 16)))
            + (bf2f((ushort)(v2.x >> 16)) + bf2f((ushort)(v3.x >> 16)))
            + (bf2f((ushort)(v4.x >> 16)) + bf2f((ushort)(v5.x >> 16)))
            + (bf2f((ushort)(v6.x >> 16)) + bf2f((ushort)(v7.x >> 16)));
        a2 += (bf2f((ushort)(v0.y & 0xffff)) + bf2f((ushort)(v1.y & 0xffff)))
            + (bf2f((ushort)(v2.y & 0xffff)) + bf2f((ushort)(v3.y & 0xffff)))
            + (bf2f((ushort)(v4.y & 0xffff)) + bf2f((ushort)(v5.y & 0xffff)))
            + (bf2f((ushort)(v6.y & 0xffff)) + bf2f((ushort)(v7.y & 0xffff)));
        a3 += (bf2f((ushort)(v0.y >> 16)) + bf2f((ushort)(v1.y >> 16)))
            + (bf2f((ushort)(v2.y >> 16)) + bf2f((ushort)(v3.y >> 16)))
            + (bf2f((ushort)(v4.y >> 16)) + bf2f((ushort)(v5.y >> 16)))
            + (bf2f((ushort)(v6.y >> 16)) + bf2f((ushort)(v7.y >> 16)));
    }
    for (; e < end; ++e) {
        int s = __builtin_nontemporal_load(&sorted_src[e]);
        uint2 v = gp[(size_t)s * 4 + sub];
        a0 += bf2f((ushort)(v.x & 0xffff));
        a1 += bf2f((ushort)(v.x >> 16));
        a2 += bf2f((ushort)(v.y & 0xffff));
        a3 += bf2f((ushort)(v.y >> 16));
    }
    float di = rsqrtf((float)cnt + 1.0f);
    union { float f[4]; unsigned long long u[2]; } cv;
    cv.f[0] = a0 * di; cv.f[1] = a1 * di; cv.f[2] = a2 * di; cv.f[3] = a3 * di;
    float* op = out + (size_t)node * OUT_CH + part * 16 + sub * 4;  // 16B aligned
    __builtin_nontemporal_store(cv.u[0], (unsigned long long*)op);
    __builtin_nontemporal_store(cv.u[1], (unsigned long long*)(op + 2));
}

// ---------------------------------------------------------------------------
// k_stats: per-channel sum and sum-of-squares of out (256 blocks only)
// ---------------------------------------------------------------------------
__global__ __launch_bounds__(768) void k_stats(const float* __restrict__ v,
                                               float* __restrict__ stats, int N) {
    __shared__ float ls[16][OUT_CH];
    __shared__ float ls2[16][OUT_CH];
    int c = threadIdx.x;   // 0..47
    int ty = threadIdx.y;  // 0..15
    float s = 0.f, s2 = 0.f;
    for (int r = blockIdx.x * 16 + ty; r < N; r += gridDim.x * 16) {
        float u = v[(size_t)r * OUT_CH + c];
        s += u;
        s2 += u * u;
    }
    ls[ty][c] = s;
    ls2[ty][c] = s2;
    __syncthreads();
    for (int h = 8; h > 0; h >>= 1) {
        if (ty < h) {
            ls[ty][c] += ls[ty + h][c];
            ls2[ty][c] += ls2[ty + h][c];
        }
        __syncthreads();
    }
    if (ty == 0) {
        atomicAdd(&stats[c], ls[0][c]);
        atomicAdd(&stats[OUT_CH + c], ls2[0][c]);
    }
}

// ---------------------------------------------------------------------------
// k_final: BN (batch stats) + ReLU, in place. GCN bias b cancels under BN.
// ---------------------------------------------------------------------------
__global__ void k_final(float* __restrict__ out, const float* __restrict__ stats,
                        const float* __restrict__ gamma,
                        const float* __restrict__ beta, int N) {
    int t = blockIdx.x * blockDim.x + threadIdx.x;
    int total = N * OUT_CH;
    if (t >= total) return;
    int c = t % OUT_CH;
    float invN = 1.0f / (float)N;
    float m = stats[c] * invN;
    float var = stats[OUT_CH + c] * invN - m * m;
    float y = (out[t] - m) * rsqrtf(var + BN_EPS) * gamma[c] + beta[c];
    out[t] = fmaxf(y, 0.0f);
}

extern "C" void kernel_launch(void* const* d_in, const int* in_sizes, int n_in,
                              void* d_out, int out_size, void* d_ws, size_t ws_size,
                              hipStream_t stream) {
    const float* x     = (const float*)d_in[0];
    const int*   ei    = (const int*)d_in[1];
    const float* W     = (const float*)d_in[2];
    // d_in[3] = b : constant per-channel offset cancels in BatchNorm -> unused
    const float* gamma = (const float*)d_in[4];
    const float* beta  = (const float*)d_in[5];
    float*       out   = (float*)d_out;

    int N = in_sizes[0] / IN_CH;     // 100000 (< 2^17 for packing)
    int E = in_sizes[1] / 2;         // 1600000
    const int* src = ei;             // edge_index[0]
    const int* dst = ei + E;         // edge_index[1]

    int nb = (N + NPB - 1) / NPB;    // 391 buckets

    // workspace layout (bytes):
    // [0, 512)          stats float[128]
    // [512, 2564)       bstart int[513]
    // [4096, 6144)      bcur int[512]
    // [8192, 10240)     bhist int[512]
    // [139264=A, +4N)   counts int[N]
    // [.., +4N)         rowstart int[N]
    // [.., +4E)         binned uint[E]
    // [.., +4E)         sorted_src int[E]
    // [.., +96N)        g bf16[3][N][16] (16B aligned)
    char* wsb = (char*)d_ws;
    float*        stats      = (float*)wsb;
    int*          bstart     = (int*)(wsb + 512);
    int*          bcur       = (int*)(wsb + 4096);
    int*          bhist      = (int*)(wsb + 8192);
    size_t A = 139264;
    int*          counts     = (int*)(wsb + A);
    int*          rowstart   = (int*)(wsb + A + (size_t)4 * N);
    unsigned int* binned     = (unsigned int*)(wsb + A + (size_t)8 * N);
    int*          sorted_src = (int*)(wsb + A + (size_t)8 * N + (size_t)4 * E);
    ushort*       g          = (ushort*)(wsb + A + (size_t)8 * N + (size_t)8 * E);

    int b = 256;
    int nchunks = (E + CHUNK - 1) / CHUNK;   // 391
    int ngemm = (N + b - 1) / b;             // 391

    // 1. zero bhist
    k_zero<<<1, 512, 0, stream>>>(bhist);
    // 2. bucket histogram (512 blocks, LDS hist, atomic flush)
    k_binhist<<<NHB, b, 0, stream>>>(dst, bhist, E);
    // 3. scan -> bstart / bcur; zero stats
    k_scanb<<<1, b, 0, stream>>>(bhist, bstart, bcur, nb, stats);
    // 4. fused: coarse counting-sort (blocks 0..nchunks) + unscaled GEMM (rest)
    k_binmm<<<nchunks + ngemm, b, 0, stream>>>(src, dst, bcur, binned, E, nchunks,
                                               x, W, g, N);
    // 5. fine sort within buckets -> counts/rowstart/sorted_src + g rescale
    k_fine<<<nb, 512, 0, stream>>>(binned, bstart, counts, rowstart, sorted_src, g, N);
    // 6. gather: 3 column-block passes (each 3.2MB g-part -> L2-resident/XCD)
    int gthreads = N * 4;
    int gblocks = (gthreads + b - 1) / b;
    for (int p = 0; p < 3; ++p)
        k_gather3<<<gblocks, b, 0, stream>>>(sorted_src, rowstart, counts, g, out, N, p);
    // 7. BN stats
    dim3 sblk(OUT_CH, 16);
    k_stats<<<256, sblk, 0, stream>>>(out, stats, N);
    // 8. BN + ReLU in place
    int totalT = N * OUT_CH;
    k_final<<<(totalT + b - 1) / b, b, 0, stream>>>(out, stats, gamma, beta, N);
}

// Round 16
// 162.535 us; speedup vs baseline: 1.0094x; 1.0094x over previous
//
#include <hip/hip_runtime.h>
#include <hip/hip_bf16.h>

#define IN_CH 48
#define OUT_CH 48
#define BN_EPS 1e-5f
#define CHUNK 4096          // edges per bin block
#define EPT   16            // edges per thread in bin role (CHUNK/256)
#define NPB   256           // nodes per bucket (bucket = dst >> 8)
#define NHB   512           // histogram blocks

__device__ __forceinline__ float bf2f(ushort u) {
    union { unsigned int i; float f; } v;
    v.i = ((unsigned int)u) << 16;
    return v.f;
}
__device__ __forceinline__ ushort f2bf(float f) {
    __hip_bfloat16 h = __float2bfloat16(f);  // round-to-nearest-even
    return *(ushort*)&h;
}

// ---------------------------------------------------------------------------
// k_zero: bhist[512] = 0 (1 block)
// ---------------------------------------------------------------------------
__global__ __launch_bounds__(512) void k_zero(int* __restrict__ bhist) {
    bhist[threadIdx.x] = 0;
}

// ---------------------------------------------------------------------------
// k_binhist: 512 blocks, LDS bucket hist, global-atomic flush, unroll-4.
// ---------------------------------------------------------------------------
__global__ __launch_bounds__(256) void k_binhist(const int* __restrict__ dst,
                                                 int* __restrict__ bhist, int E) {
    __shared__ int h[512];
    int t = threadIdx.x;
    h[t] = 0; h[t + 256] = 0;
    __syncthreads();
    const int stride = NHB * 256;
    int e = blockIdx.x * 256 + t;
    for (; e + 3 * stride < E; e += 4 * stride) {
        int d0 = dst[e];
        int d1 = dst[e + stride];
        int d2 = dst[e + 2 * stride];
        int d3 = dst[e + 3 * stride];
        atomicAdd(&h[d0 >> 8], 1);
        atomicAdd(&h[d1 >> 8], 1);
        atomicAdd(&h[d2 >> 8], 1);
        atomicAdd(&h[d3 >> 8], 1);
    }
    for (; e < E; e += stride) atomicAdd(&h[dst[e] >> 8], 1);
    __syncthreads();
    if (h[t]) atomicAdd(&bhist[t], h[t]);
    if (h[t + 256]) atomicAdd(&bhist[t + 256], h[t + 256]);
}

// ---------------------------------------------------------------------------
// k_scanb: exclusive scan of bhist -> bstart, bcur.
// ---------------------------------------------------------------------------
__global__ __launch_bounds__(256) void k_scanb(const int* __restrict__ bhist,
                                               int* __restrict__ bstart,
                                               int* __restrict__ bcur, int nb) {
    __shared__ int sc[256];
    int t = threadIdx.x;
    int i0 = 2 * t, i1 = 2 * t + 1;
    int a0 = bhist[i0];
    int a1 = bhist[i1];
    int ps = a0 + a1;
    sc[t] = ps;
    __syncthreads();
    for (int off = 1; off < 256; off <<= 1) {
        int v = (t >= off) ? sc[t - off] : 0;
        __syncthreads();
        sc[t] += v;
        __syncthreads();
    }
    int excl = sc[t] - ps;
    bstart[i0] = excl;
    bstart[i1] = excl + a0;
    if (i0 < nb) bcur[i0] = excl;
    if (i1 < nb) bcur[i1] = excl + a0;
    if (t == 255) bstart[512] = sc[255];  // == E
}

// ---------------------------------------------------------------------------
// k_binmm: role-split fusion. Blocks [0, nchunks): LDS counting-sort of a
// 4096-edge chunk. Blocks [nchunks, ..): UNSCALED node GEMM g = bf16(x@W)
// (dinv applied later in k_fine once counts exist). LDS union'd.
// ---------------------------------------------------------------------------
union alignas(16) SMem {
    struct {
        int hist[512];
        int hbase[513];
        int sc[256];
        int gb[512];
        unsigned int stage[CHUNK];
        short stagebk[CHUNK];
    } bin;
    float Wl[IN_CH * OUT_CH];
};

__global__ __launch_bounds__(256) void k_binmm(const int* __restrict__ src,
                                               const int* __restrict__ dst,
                                               int* __restrict__ bcur,
                                               unsigned int* __restrict__ binned,
                                               int E, int nchunks,
                                               const float* __restrict__ x,
                                               const float* __restrict__ W,
                                               ushort* __restrict__ g, int N) {
    __shared__ SMem sm;
    int t = threadIdx.x;

    if (blockIdx.x < nchunks) {
        // ------------------- bin role -------------------
        int e0 = blockIdx.x * CHUNK;
        int n = min(CHUNK, E - e0);

        sm.bin.hist[t] = 0; sm.bin.hist[t + 256] = 0;
        __syncthreads();

        unsigned int w[EPT];
        short bb[EPT];
#pragma unroll
        for (int k = 0; k < EPT; ++k) {
            int i = t + k * 256;
            if (i < n) {
                int e = e0 + i;
                int s = src[e], d = dst[e];
                int b = d >> 8;
                w[k] = (unsigned int)s | ((unsigned int)(d & 255) << 17);
                bb[k] = (short)b;
                atomicAdd(&sm.bin.hist[b], 1);
            } else bb[k] = -1;
        }
        __syncthreads();
        int a0 = sm.bin.hist[2 * t], a1 = sm.bin.hist[2 * t + 1];
        int ps = a0 + a1;
        sm.bin.sc[t] = ps;
        __syncthreads();
        for (int off = 1; off < 256; off <<= 1) {
            int v = (t >= off) ? sm.bin.sc[t - off] : 0;
            __syncthreads();
            sm.bin.sc[t] += v;
            __syncthreads();
        }
        int excl = sm.bin.sc[t] - ps;
        sm.bin.hbase[2 * t] = excl;
        sm.bin.hbase[2 * t + 1] = excl + a0;
        if (t == 255) sm.bin.hbase[512] = sm.bin.sc[255];  // == n
        __syncthreads();
        sm.bin.hist[2 * t] = excl;            // cursors
        sm.bin.hist[2 * t + 1] = excl + a0;
        __syncthreads();
#pragma unroll
        for (int k = 0; k < EPT; ++k) {
            if (bb[k] >= 0) {
                int pos = atomicAdd(&sm.bin.hist[bb[k]], 1);
                sm.bin.stage[pos] = w[k];
                sm.bin.stagebk[pos] = bb[k];
            }
        }
        __syncthreads();
        for (int b = t; b < 512; b += 256) {
            int cnt = sm.bin.hbase[b + 1] - sm.bin.hbase[b];
            if (cnt > 0) sm.bin.gb[b] = atomicAdd(&bcur[b], cnt) - sm.bin.hbase[b];
        }
        __syncthreads();
        for (int j = t; j < n; j += 256) {
            int bk = sm.bin.stagebk[j];
            binned[sm.bin.gb[bk] + j] = sm.bin.stage[j];
        }
    } else {
        // ------------------- gemm role (unscaled) -------------------
        for (int idx = t; idx < IN_CH * OUT_CH / 4; idx += 256)
            ((float4*)sm.Wl)[idx] = ((const float4*)W)[idx];
        __syncthreads();

        int i = (blockIdx.x - nchunks) * 256 + t;
        if (i >= N) return;

        float xr[IN_CH];
        const float4* xp = (const float4*)(x + (size_t)i * IN_CH);
#pragma unroll
        for (int k = 0; k < IN_CH / 4; ++k) {
            float4 v = xp[k];
            xr[4 * k] = v.x; xr[4 * k + 1] = v.y; xr[4 * k + 2] = v.z; xr[4 * k + 3] = v.w;
        }

        ushort row[OUT_CH];
#pragma unroll
        for (int c4 = 0; c4 < OUT_CH / 4; ++c4) {
            float4 acc = make_float4(0.f, 0.f, 0.f, 0.f);
#pragma unroll
            for (int k = 0; k < IN_CH; ++k) {
                float4 wv = ((const float4*)sm.Wl)[k * (OUT_CH / 4) + c4];
                acc.x += xr[k] * wv.x; acc.y += xr[k] * wv.y;
                acc.z += xr[k] * wv.z; acc.w += xr[k] * wv.w;
            }
            row[4 * c4 + 0] = f2bf(acc.x);
            row[4 * c4 + 1] = f2bf(acc.y);
            row[4 * c4 + 2] = f2bf(acc.z);
            row[4 * c4 + 3] = f2bf(acc.w);
        }
        uint4* gp = (uint4*)(g + (size_t)i * OUT_CH);  // 96B row, 16B aligned
#pragma unroll
        for (int j = 0; j < 6; ++j) gp[j] = ((uint4*)row)[j];
    }
}

// ---------------------------------------------------------------------------
// k_fine: one block per bucket. LDS hist over binned -> counts + rowstart,
// scatter src ids into the bucket's contiguous window, then RESCALE the
// bucket's g rows by dinv (counts live in LDS; 24KB/block coalesced).
// ---------------------------------------------------------------------------
__global__ __launch_bounds__(512) void k_fine(const unsigned int* __restrict__ binned,
                                              const int* __restrict__ bstart,
                                              int* __restrict__ counts,
                                              int* __restrict__ rowstart,
                                              int* __restrict__ sorted_src,
                                              ushort* __restrict__ g, int N) {
    __shared__ int cnt[256];
    __shared__ int sc[256];
    __shared__ int cur[256];
    __shared__ float sdinv[256];
    int b = blockIdx.x, t = threadIdx.x;
    int node0 = b << 8;
    int nn = min(NPB, N - node0);
    if (t < 256) cnt[t] = 0;
    __syncthreads();
    int e0 = bstart[b], e1 = bstart[b + 1];
    for (int e = e0 + t; e < e1; e += 512)
        atomicAdd(&cnt[binned[e] >> 17], 1);
    __syncthreads();
    if (t < 256) sc[t] = cnt[t];
    __syncthreads();
    for (int off = 1; off < 256; off <<= 1) {
        int v = 0;
        if (t < 256 && t >= off) v = sc[t - off];
        __syncthreads();
        if (t < 256) sc[t] += v;
        __syncthreads();
    }
    if (t < 256) {
        int excl = sc[t] - cnt[t];
        cur[t] = e0 + excl;
        sdinv[t] = rsqrtf((float)cnt[t] + 1.0f);
        if (t < nn) {
            counts[node0 + t] = cnt[t];
            rowstart[node0 + t] = e0 + excl;
        }
    }
    __syncthreads();
    for (int e = e0 + t; e < e1; e += 512) {
        unsigned int w = binned[e];
        int dl = (int)(w >> 17);
        int pos = atomicAdd(&cur[dl], 1);
        sorted_src[pos] = (int)(w & 0x1ffff);
    }
    // rescale this bucket's g rows: g[node] *= dinv[node]
    unsigned int* gw = (unsigned int*)(g + (size_t)node0 * OUT_CH);
    int words = nn * (OUT_CH / 2);  // 24 words per row
    for (int i = t; i < words; i += 512) {
        int r = i / (OUT_CH / 2);
        float d = sdinv[r];
        unsigned int u = gw[i];
        float lo = bf2f((ushort)(u & 0xffff)) * d;
        float hi = bf2f((ushort)(u >> 16)) * d;
        gw[i] = (unsigned int)f2bf(lo) | ((unsigned int)f2bf(hi) << 16);
    }
}

// ---------------------------------------------------------------------------
// k_gather: one thread per (node, 4-channel group). uint2 loads (4 bf16),
// 12 lanes per row, 1.2M threads (proven MLP sweet spot), unroll-8.
// BN-stats fused as NON-atomic per-block partials: LDS reduce, one coalesced
// 384B spart store per block (round-7's global-atomic storm avoided).
// ---------------------------------------------------------------------------
__global__ __launch_bounds__(256) void k_gather(const int* __restrict__ sorted_src,
                                                const int* __restrict__ rowstart,
                                                const int* __restrict__ counts,
                                                const ushort* __restrict__ g,
                                                float* __restrict__ out,
                                                float* __restrict__ spart, int N) {
    __shared__ float ssum[OUT_CH];
    __shared__ float ssq[OUT_CH];
    int lt = threadIdx.x;
    if (lt < OUT_CH) { ssum[lt] = 0.0f; ssq[lt] = 0.0f; }
    __syncthreads();

    int t = blockIdx.x * 256 + lt;
    if (t < N * 12) {
        int node = t / 12;
        int sub = t - node * 12;          // 0..11 -> channels [4*sub, 4*sub+4)
        const uint2* gp = (const uint2*)g;  // row = 12 x uint2 (8B each)
        int cnt = counts[node];
        int e = rowstart[node];
        int end = e + cnt;

        uint2 sv = gp[(size_t)node * 12 + sub];  // self loop
        float a0 = bf2f((ushort)(sv.x & 0xffff));
        float a1 = bf2f((ushort)(sv.x >> 16));
        float a2 = bf2f((ushort)(sv.y & 0xffff));
        float a3 = bf2f((ushort)(sv.y >> 16));

        for (; e + 8 <= end; e += 8) {
            int s0 = sorted_src[e];
            int s1 = sorted_src[e + 1];
            int s2 = sorted_src[e + 2];
            int s3 = sorted_src[e + 3];
            int s4 = sorted_src[e + 4];
            int s5 = sorted_src[e + 5];
            int s6 = sorted_src[e + 6];
            int s7 = sorted_src[e + 7];
            uint2 v0 = gp[(size_t)s0 * 12 + sub];
            uint2 v1 = gp[(size_t)s1 * 12 + sub];
            uint2 v2 = gp[(size_t)s2 * 12 + sub];
            uint2 v3 = gp[(size_t)s3 * 12 + sub];
            uint2 v4 = gp[(size_t)s4 * 12 + sub];
            uint2 v5 = gp[(size_t)s5 * 12 + sub];
            uint2 v6 = gp[(size_t)s6 * 12 + sub];
            uint2 v7 = gp[(size_t)s7 * 12 + sub];
            a0 += (bf2f((ushort)(v0.x & 0xffff)) + bf2f((ushort)(v1.x & 0xffff)))
                + (bf2f((ushort)(v2.x & 0xffff)) + bf2f((ushort)(v3.x & 0xffff)))
                + (bf2f((ushort)(v4.x & 0xffff)) + bf2f((ushort)(v5.x & 0xffff)))
                + (bf2f((ushort)(v6.x & 0xffff)) + bf2f((ushort)(v7.x & 0xffff)));
            a1 += (bf2f((ushort)(v0.x >> 16)) + bf2f((ushort)(v1.x >> 16)))
                + (bf2f((ushort)(v2.x >> 16)) + bf2f((ushort)(v3.x >> 16)))
                + (bf2f((ushort)(v4.x >> 16)) + bf2f((ushort)(v5.x >> 16)))
                + (bf2f((ushort)(v6.x >> 16)) + bf2f((ushort)(v7.x >> 16)));
            a2 += (bf2f((ushort)(v0.y & 0xffff)) + bf2f((ushort)(v1.y & 0xffff)))
                + (bf2f((ushort)(v2.y & 0xffff)) + bf2f((ushort)(v3.y & 0xffff)))
                + (bf2f((ushort)(v4.y & 0xffff)) + bf2f((ushort)(v5.y & 0xffff)))
                + (bf2f((ushort)(v6.y & 0xffff)) + bf2f((ushort)(v7.y & 0xffff)));
            a3 += (bf2f((ushort)(v0.y >> 16)) + bf2f((ushort)(v1.y >> 16)))
                + (bf2f((ushort)(v2.y >> 16)) + bf2f((ushort)(v3.y >> 16)))
                + (bf2f((ushort)(v4.y >> 16)) + bf2f((ushort)(v5.y >> 16)))
                + (bf2f((ushort)(v6.y >> 16)) + bf2f((ushort)(v7.y >> 16)));
        }
        for (; e + 4 <= end; e += 4) {
            int s0 = sorted_src[e];
            int s1 = sorted_src[e + 1];
            int s2 = sorted_src[e + 2];
            int s3 = sorted_src[e + 3];
            uint2 v0 = gp[(size_t)s0 * 12 + sub];
            uint2 v1 = gp[(size_t)s1 * 12 + sub];
            uint2 v2 = gp[(size_t)s2 * 12 + sub];
            uint2 v3 = gp[(size_t)s3 * 12 + sub];
            a0 += bf2f((ushort)(v0.x & 0xffff)) + bf2f((ushort)(v1.x & 0xffff))
                + bf2f((ushort)(v2.x & 0xffff)) + bf2f((ushort)(v3.x & 0xffff));
            a1 += bf2f((ushort)(v0.x >> 16)) + bf2f((ushort)(v1.x >> 16))
                + bf2f((ushort)(v2.x >> 16)) + bf2f((ushort)(v3.x >> 16));
            a2 += bf2f((ushort)(v0.y & 0xffff)) + bf2f((ushort)(v1.y & 0xffff))
                + bf2f((ushort)(v2.y & 0xffff)) + bf2f((ushort)(v3.y & 0xffff));
            a3 += bf2f((ushort)(v0.y >> 16)) + bf2f((ushort)(v1.y >> 16))
                + bf2f((ushort)(v2.y >> 16)) + bf2f((ushort)(v3.y >> 16));
        }
        for (; e < end; ++e) {
            int s = sorted_src[e];
            uint2 v = gp[(size_t)s * 12 + sub];
            a0 += bf2f((ushort)(v.x & 0xffff));
            a1 += bf2f((ushort)(v.x >> 16));
            a2 += bf2f((ushort)(v.y & 0xffff));
            a3 += bf2f((ushort)(v.y >> 16));
        }
        float di = rsqrtf((float)cnt + 1.0f);
        float4 r;
        r.x = a0 * di; r.y = a1 * di; r.z = a2 * di; r.w = a3 * di;
        ((float4*)out)[(size_t)node * 12 + sub] = r;
        // fused BN-stats partials (LDS only; no global atomics)
        int c = 4 * sub;
        atomicAdd(&ssum[c + 0], r.x);
        atomicAdd(&ssum[c + 1], r.y);
        atomicAdd(&ssum[c + 2], r.z);
        atomicAdd(&ssum[c + 3], r.w);
        atomicAdd(&ssq[c + 0], r.x * r.x);
        atomicAdd(&ssq[c + 1], r.y * r.y);
        atomicAdd(&ssq[c + 2], r.z * r.z);
        atomicAdd(&ssq[c + 3], r.w * r.w);
    }
    __syncthreads();
    if (lt < OUT_CH) {
        spart[(size_t)blockIdx.x * 96 + lt] = ssum[lt];
        spart[(size_t)blockIdx.x * 96 + OUT_CH + lt] = ssq[lt];
    }
}

// ---------------------------------------------------------------------------
// k_redstats: stats[c] = sum over blocks of spart[blk][c]. 96 blocks,
// plain store (no stats zero-init needed).
// ---------------------------------------------------------------------------
__global__ __launch_bounds__(256) void k_redstats(const float* __restrict__ spart,
                                                  float* __restrict__ stats, int nblk) {
    __shared__ float l[256];
    int c = blockIdx.x;   // 0..95
    int t = threadIdx.x;
    float s = 0.f;
    for (int b = t; b < nblk; b += 256) s += spart[(size_t)b * 96 + c];
    l[t] = s;
    __syncthreads();
    for (int h = 128; h > 0; h >>= 1) {
        if (t < h) l[t] += l[t + h];
        __syncthreads();
    }
    if (t == 0) stats[c] = l[0];
}

// ---------------------------------------------------------------------------
// k_final: BN (batch stats) + ReLU, in place. GCN bias b cancels under BN.
// ---------------------------------------------------------------------------
__global__ void k_final(float* __restrict__ out, const float* __restrict__ stats,
                        const float* __restrict__ gamma,
                        const float* __restrict__ beta, int N) {
    int t = blockIdx.x * blockDim.x + threadIdx.x;
    int total = N * OUT_CH;
    if (t >= total) return;
    int c = t % OUT_CH;
    float invN = 1.0f / (float)N;
    float m = stats[c] * invN;
    float var = stats[OUT_CH + c] * invN - m * m;
    float y = (out[t] - m) * rsqrtf(var + BN_EPS) * gamma[c] + beta[c];
    out[t] = fmaxf(y, 0.0f);
}

extern "C" void kernel_launch(void* const* d_in, const int* in_sizes, int n_in,
                              void* d_out, int out_size, void* d_ws, size_t ws_size,
                              hipStream_t stream) {
    const float* x     = (const float*)d_in[0];
    const int*   ei    = (const int*)d_in[1];
    const float* W     = (const float*)d_in[2];
    // d_in[3] = b : constant per-channel offset cancels in BatchNorm -> unused
    const float* gamma = (const float*)d_in[4];
    const float* beta  = (const float*)d_in[5];
    float*       out   = (float*)d_out;

    int N = in_sizes[0] / IN_CH;     // 100000 (< 2^17 for packing)
    int E = in_sizes[1] / 2;         // 1600000
    const int* src = ei;             // edge_index[0]
    const int* dst = ei + E;         // edge_index[1]

    int nb = (N + NPB - 1) / NPB;    // 391 buckets

    // workspace layout (bytes):
    // [0, 512)          stats float[128]
    // [512, 2564)       bstart int[513]
    // [4096, 6144)      bcur int[512]
    // [8192, 10240)     bhist int[512]
    // [139264=A, +4N)   counts int[N]
    // [.., +4N)         rowstart int[N]
    // [.., +4E)         binned uint[E]
    // [.., +4E)         sorted_src int[E]
    // [.., +96N)        g bf16[N*48] (16B aligned)
    // [.., +~1.8MB)     spart float[gblocks*96]
    char* wsb = (char*)d_ws;
    float*        stats      = (float*)wsb;
    int*          bstart     = (int*)(wsb + 512);
    int*          bcur       = (int*)(wsb + 4096);
    int*          bhist      = (int*)(wsb + 8192);
    size_t A = 139264;
    int*          counts     = (int*)(wsb + A);
    int*          rowstart   = (int*)(wsb + A + (size_t)4 * N);
    unsigned int* binned     = (unsigned int*)(wsb + A + (size_t)8 * N);
    int*          sorted_src = (int*)(wsb + A + (size_t)8 * N + (size_t)4 * E);
    ushort*       g          = (ushort*)(wsb + A + (size_t)8 * N + (size_t)8 * E);
    float*        spart      = (float*)(wsb + A + (size_t)8 * N + (size_t)8 * E + (size_t)96 * N);

    int b = 256;
    int nchunks = (E + CHUNK - 1) / CHUNK;   // 391
    int ngemm = (N + b - 1) / b;             // 391

    // 1. zero bhist
    k_zero<<<1, 512, 0, stream>>>(bhist);
    // 2. bucket histogram (512 blocks, LDS hist, atomic flush)
    k_binhist<<<NHB, b, 0, stream>>>(dst, bhist, E);
    // 3. scan -> bstart / bcur
    k_scanb<<<1, b, 0, stream>>>(bhist, bstart, bcur, nb);
    // 4. fused: coarse counting-sort (blocks 0..nchunks) + unscaled GEMM (rest)
    k_binmm<<<nchunks + ngemm, b, 0, stream>>>(src, dst, bcur, binned, E, nchunks,
                                               x, W, g, N);
    // 5. fine sort within buckets -> counts/rowstart/sorted_src + g rescale
    k_fine<<<nb, 512, 0, stream>>>(binned, bstart, counts, rowstart, sorted_src, g, N);
    // 6. gather + self loop + dst dinv + fused stats partials (non-atomic)
    int gthreads = N * 12;
    int gblocks = (gthreads + b - 1) / b;    // 4688
    k_gather<<<gblocks, b, 0, stream>>>(sorted_src, rowstart, counts, g, out, spart, N);
    // 7. reduce stats partials (96 blocks, plain store)
    k_redstats<<<2 * OUT_CH, b, 0, stream>>>(spart, stats, gblocks);
    // 8. BN + ReLU in place
    int totalT = N * OUT_CH;
    k_final<<<(totalT + b - 1) / b, b, 0, stream>>>(out, stats, gamma, beta, N);
}

// Round 17
// 129.299 us; speedup vs baseline: 1.2688x; 1.2570x over previous
//
#include <hip/hip_runtime.h>
#include <hip/hip_bf16.h>

#define IN_CH 48
#define OUT_CH 48
#define BN_EPS 1e-5f
#define CHUNK 4096          // edges per bin block
#define EPT   16            // edges per thread in bin role (CHUNK/256)
#define NPB   256           // nodes per bucket (bucket = dst >> 8)
#define NHB   512           // histogram blocks

__device__ __forceinline__ float bf2f(ushort u) {
    union { unsigned int i; float f; } v;
    v.i = ((unsigned int)u) << 16;
    return v.f;
}
__device__ __forceinline__ ushort f2bf(float f) {
    __hip_bfloat16 h = __float2bfloat16(f);  // round-to-nearest-even
    return *(ushort*)&h;
}

// ---------------------------------------------------------------------------
// k_zero: bhist[512] = 0 (1 block)
// ---------------------------------------------------------------------------
__global__ __launch_bounds__(512) void k_zero(int* __restrict__ bhist) {
    bhist[threadIdx.x] = 0;
}

// ---------------------------------------------------------------------------
// k_binhist: 512 blocks, LDS bucket hist, global-atomic flush, unroll-4.
// ---------------------------------------------------------------------------
__global__ __launch_bounds__(256) void k_binhist(const int* __restrict__ dst,
                                                 int* __restrict__ bhist, int E) {
    __shared__ int h[512];
    int t = threadIdx.x;
    h[t] = 0; h[t + 256] = 0;
    __syncthreads();
    const int stride = NHB * 256;
    int e = blockIdx.x * 256 + t;
    for (; e + 3 * stride < E; e += 4 * stride) {
        int d0 = dst[e];
        int d1 = dst[e + stride];
        int d2 = dst[e + 2 * stride];
        int d3 = dst[e + 3 * stride];
        atomicAdd(&h[d0 >> 8], 1);
        atomicAdd(&h[d1 >> 8], 1);
        atomicAdd(&h[d2 >> 8], 1);
        atomicAdd(&h[d3 >> 8], 1);
    }
    for (; e < E; e += stride) atomicAdd(&h[dst[e] >> 8], 1);
    __syncthreads();
    if (h[t]) atomicAdd(&bhist[t], h[t]);
    if (h[t + 256]) atomicAdd(&bhist[t + 256], h[t + 256]);
}

// ---------------------------------------------------------------------------
// k_scanb: exclusive scan of bhist -> bstart, bcur. Zeroes stats[128].
// ---------------------------------------------------------------------------
__global__ __launch_bounds__(256) void k_scanb(const int* __restrict__ bhist,
                                               int* __restrict__ bstart,
                                               int* __restrict__ bcur, int nb,
                                               float* __restrict__ stats) {
    __shared__ int sc[256];
    int t = threadIdx.x;
    if (t < 128) stats[t] = 0.0f;
    int i0 = 2 * t, i1 = 2 * t + 1;
    int a0 = bhist[i0];
    int a1 = bhist[i1];
    int ps = a0 + a1;
    sc[t] = ps;
    __syncthreads();
    for (int off = 1; off < 256; off <<= 1) {
        int v = (t >= off) ? sc[t - off] : 0;
        __syncthreads();
        sc[t] += v;
        __syncthreads();
    }
    int excl = sc[t] - ps;
    bstart[i0] = excl;
    bstart[i1] = excl + a0;
    if (i0 < nb) bcur[i0] = excl;
    if (i1 < nb) bcur[i1] = excl + a0;
    if (t == 255) bstart[512] = sc[255];  // == E
}

// ---------------------------------------------------------------------------
// k_binmm: role-split fusion. Blocks [0, nchunks): LDS counting-sort of a
// 4096-edge chunk. Blocks [nchunks, ..): UNSCALED node GEMM g = bf16(x@W)
// (dinv applied later in k_fine once counts exist). LDS union'd.
// ---------------------------------------------------------------------------
union alignas(16) SMem {
    struct {
        int hist[512];
        int hbase[513];
        int sc[256];
        int gb[512];
        unsigned int stage[CHUNK];
        short stagebk[CHUNK];
    } bin;
    float Wl[IN_CH * OUT_CH];
};

__global__ __launch_bounds__(256) void k_binmm(const int* __restrict__ src,
                                               const int* __restrict__ dst,
                                               int* __restrict__ bcur,
                                               unsigned int* __restrict__ binned,
                                               int E, int nchunks,
                                               const float* __restrict__ x,
                                               const float* __restrict__ W,
                                               ushort* __restrict__ g, int N) {
    __shared__ SMem sm;
    int t = threadIdx.x;

    if (blockIdx.x < nchunks) {
        // ------------------- bin role -------------------
        int e0 = blockIdx.x * CHUNK;
        int n = min(CHUNK, E - e0);

        sm.bin.hist[t] = 0; sm.bin.hist[t + 256] = 0;
        __syncthreads();

        unsigned int w[EPT];
        short bb[EPT];
#pragma unroll
        for (int k = 0; k < EPT; ++k) {
            int i = t + k * 256;
            if (i < n) {
                int e = e0 + i;
                int s = src[e], d = dst[e];
                int b = d >> 8;
                w[k] = (unsigned int)s | ((unsigned int)(d & 255) << 17);
                bb[k] = (short)b;
                atomicAdd(&sm.bin.hist[b], 1);
            } else bb[k] = -1;
        }
        __syncthreads();
        int a0 = sm.bin.hist[2 * t], a1 = sm.bin.hist[2 * t + 1];
        int ps = a0 + a1;
        sm.bin.sc[t] = ps;
        __syncthreads();
        for (int off = 1; off < 256; off <<= 1) {
            int v = (t >= off) ? sm.bin.sc[t - off] : 0;
            __syncthreads();
            sm.bin.sc[t] += v;
            __syncthreads();
        }
        int excl = sm.bin.sc[t] - ps;
        sm.bin.hbase[2 * t] = excl;
        sm.bin.hbase[2 * t + 1] = excl + a0;
        if (t == 255) sm.bin.hbase[512] = sm.bin.sc[255];  // == n
        __syncthreads();
        sm.bin.hist[2 * t] = excl;            // cursors
        sm.bin.hist[2 * t + 1] = excl + a0;
        __syncthreads();
#pragma unroll
        for (int k = 0; k < EPT; ++k) {
            if (bb[k] >= 0) {
                int pos = atomicAdd(&sm.bin.hist[bb[k]], 1);
                sm.bin.stage[pos] = w[k];
                sm.bin.stagebk[pos] = bb[k];
            }
        }
        __syncthreads();
        for (int b = t; b < 512; b += 256) {
            int cnt = sm.bin.hbase[b + 1] - sm.bin.hbase[b];
            if (cnt > 0) sm.bin.gb[b] = atomicAdd(&bcur[b], cnt) - sm.bin.hbase[b];
        }
        __syncthreads();
        for (int j = t; j < n; j += 256) {
            int bk = sm.bin.stagebk[j];
            binned[sm.bin.gb[bk] + j] = sm.bin.stage[j];
        }
    } else {
        // ------------------- gemm role (unscaled) -------------------
        for (int idx = t; idx < IN_CH * OUT_CH / 4; idx += 256)
            ((float4*)sm.Wl)[idx] = ((const float4*)W)[idx];
        __syncthreads();

        int i = (blockIdx.x - nchunks) * 256 + t;
        if (i >= N) return;

        float xr[IN_CH];
        const float4* xp = (const float4*)(x + (size_t)i * IN_CH);
#pragma unroll
        for (int k = 0; k < IN_CH / 4; ++k) {
            float4 v = xp[k];
            xr[4 * k] = v.x; xr[4 * k + 1] = v.y; xr[4 * k + 2] = v.z; xr[4 * k + 3] = v.w;
        }

        ushort row[OUT_CH];
#pragma unroll
        for (int c4 = 0; c4 < OUT_CH / 4; ++c4) {
            float4 acc = make_float4(0.f, 0.f, 0.f, 0.f);
#pragma unroll
            for (int k = 0; k < IN_CH; ++k) {
                float4 wv = ((const float4*)sm.Wl)[k * (OUT_CH / 4) + c4];
                acc.x += xr[k] * wv.x; acc.y += xr[k] * wv.y;
                acc.z += xr[k] * wv.z; acc.w += xr[k] * wv.w;
            }
            row[4 * c4 + 0] = f2bf(acc.x);
            row[4 * c4 + 1] = f2bf(acc.y);
            row[4 * c4 + 2] = f2bf(acc.z);
            row[4 * c4 + 3] = f2bf(acc.w);
        }
        uint4* gp = (uint4*)(g + (size_t)i * OUT_CH);  // 96B row, 16B aligned
#pragma unroll
        for (int j = 0; j < 6; ++j) gp[j] = ((uint4*)row)[j];
    }
}

// ---------------------------------------------------------------------------
// k_fine: one block per bucket. LDS hist over binned -> counts + rowstart,
// scatter src ids into the bucket's contiguous window, then RESCALE the
// bucket's g rows by dinv (counts live in LDS; 24KB/block coalesced).
// ---------------------------------------------------------------------------
__global__ __launch_bounds__(512) void k_fine(const unsigned int* __restrict__ binned,
                                              const int* __restrict__ bstart,
                                              int* __restrict__ counts,
                                              int* __restrict__ rowstart,
                                              int* __restrict__ sorted_src,
                                              ushort* __restrict__ g, int N) {
    __shared__ int cnt[256];
    __shared__ int sc[256];
    __shared__ int cur[256];
    __shared__ float sdinv[256];
    int b = blockIdx.x, t = threadIdx.x;
    int node0 = b << 8;
    int nn = min(NPB, N - node0);
    if (t < 256) cnt[t] = 0;
    __syncthreads();
    int e0 = bstart[b], e1 = bstart[b + 1];
    for (int e = e0 + t; e < e1; e += 512)
        atomicAdd(&cnt[binned[e] >> 17], 1);
    __syncthreads();
    if (t < 256) sc[t] = cnt[t];
    __syncthreads();
    for (int off = 1; off < 256; off <<= 1) {
        int v = 0;
        if (t < 256 && t >= off) v = sc[t - off];
        __syncthreads();
        if (t < 256) sc[t] += v;
        __syncthreads();
    }
    if (t < 256) {
        int excl = sc[t] - cnt[t];
        cur[t] = e0 + excl;
        sdinv[t] = rsqrtf((float)cnt[t] + 1.0f);
        if (t < nn) {
            counts[node0 + t] = cnt[t];
            rowstart[node0 + t] = e0 + excl;
        }
    }
    __syncthreads();
    for (int e = e0 + t; e < e1; e += 512) {
        unsigned int w = binned[e];
        int dl = (int)(w >> 17);
        int pos = atomicAdd(&cur[dl], 1);
        sorted_src[pos] = (int)(w & 0x1ffff);
    }
    // rescale this bucket's g rows: g[node] *= dinv[node]
    unsigned int* gw = (unsigned int*)(g + (size_t)node0 * OUT_CH);
    int words = nn * (OUT_CH / 2);  // 24 words per row
    for (int i = t; i < words; i += 512) {
        int r = i / (OUT_CH / 2);
        float d = sdinv[r];
        unsigned int u = gw[i];
        float lo = bf2f((ushort)(u & 0xffff)) * d;
        float hi = bf2f((ushort)(u >> 16)) * d;
        gw[i] = (unsigned int)f2bf(lo) | ((unsigned int)f2bf(hi) << 16);
    }
}

// ---------------------------------------------------------------------------
// k_gather: one thread per (node, 4-channel group). uint2 loads (4 bf16),
// 12 lanes per row (1.2M threads = proven MLP sweet spot), unroll-8.
// NO fused stats: rounds 7/12/16 all showed any reduction epilogue on this
// latency-bound kernel costs ~2x (tail threads + barrier + LDS contention).
// ---------------------------------------------------------------------------
__global__ __launch_bounds__(256) void k_gather(const int* __restrict__ sorted_src,
                                                const int* __restrict__ rowstart,
                                                const int* __restrict__ counts,
                                                const ushort* __restrict__ g,
                                                float* __restrict__ out, int N) {
    int t = blockIdx.x * blockDim.x + threadIdx.x;
    if (t >= N * 12) return;
    int node = t / 12;
    int sub = t - node * 12;          // 0..11 -> channels [4*sub, 4*sub+4)
    const uint2* gp = (const uint2*)g;  // row = 12 x uint2 (8B each)
    int cnt = counts[node];
    int e = rowstart[node];
    int end = e + cnt;

    uint2 sv = gp[(size_t)node * 12 + sub];  // self loop
    float a0 = bf2f((ushort)(sv.x & 0xffff));
    float a1 = bf2f((ushort)(sv.x >> 16));
    float a2 = bf2f((ushort)(sv.y & 0xffff));
    float a3 = bf2f((ushort)(sv.y >> 16));

    for (; e + 8 <= end; e += 8) {
        int s0 = sorted_src[e];
        int s1 = sorted_src[e + 1];
        int s2 = sorted_src[e + 2];
        int s3 = sorted_src[e + 3];
        int s4 = sorted_src[e + 4];
        int s5 = sorted_src[e + 5];
        int s6 = sorted_src[e + 6];
        int s7 = sorted_src[e + 7];
        uint2 v0 = gp[(size_t)s0 * 12 + sub];
        uint2 v1 = gp[(size_t)s1 * 12 + sub];
        uint2 v2 = gp[(size_t)s2 * 12 + sub];
        uint2 v3 = gp[(size_t)s3 * 12 + sub];
        uint2 v4 = gp[(size_t)s4 * 12 + sub];
        uint2 v5 = gp[(size_t)s5 * 12 + sub];
        uint2 v6 = gp[(size_t)s6 * 12 + sub];
        uint2 v7 = gp[(size_t)s7 * 12 + sub];
        a0 += (bf2f((ushort)(v0.x & 0xffff)) + bf2f((ushort)(v1.x & 0xffff)))
            + (bf2f((ushort)(v2.x & 0xffff)) + bf2f((ushort)(v3.x & 0xffff)))
            + (bf2f((ushort)(v4.x & 0xffff)) + bf2f((ushort)(v5.x & 0xffff)))
            + (bf2f((ushort)(v6.x & 0xffff)) + bf2f((ushort)(v7.x & 0xffff)));
        a1 += (bf2f((ushort)(v0.x >> 16)) + bf2f((ushort)(v1.x >> 16)))
            + (bf2f((ushort)(v2.x >> 16)) + bf2f((ushort)(v3.x >> 16)))
            + (bf2f((ushort)(v4.x >> 16)) + bf2f((ushort)(v5.x >> 16)))
            + (bf2f((ushort)(v6.x >> 16)) + bf2f((ushort)(v7.x >> 16)));
        a2 += (bf2f((ushort)(v0.y & 0xffff)) + bf2f((ushort)(v1.y & 0xffff)))
            + (bf2f((ushort)(v2.y & 0xffff)) + bf2f((ushort)(v3.y & 0xffff)))
            + (bf2f((ushort)(v4.y & 0xffff)) + bf2f((ushort)(v5.y & 0xffff)))
            + (bf2f((ushort)(v6.y & 0xffff)) + bf2f((ushort)(v7.y & 0xffff)));
        a3 += (bf2f((ushort)(v0.y >> 16)) + bf2f((ushort)(v1.y >> 16)))
            + (bf2f((ushort)(v2.y >> 16)) + bf2f((ushort)(v3.y >> 16)))
            + (bf2f((ushort)(v4.y >> 16)) + bf2f((ushort)(v5.y >> 16)))
            + (bf2f((ushort)(v6.y >> 16)) + bf2f((ushort)(v7.y >> 16)));
    }
    for (; e + 4 <= end; e += 4) {
        int s0 = sorted_src[e];
        int s1 = sorted_src[e + 1];
        int s2 = sorted_src[e + 2];
        int s3 = sorted_src[e + 3];
        uint2 v0 = gp[(size_t)s0 * 12 + sub];
        uint2 v1 = gp[(size_t)s1 * 12 + sub];
        uint2 v2 = gp[(size_t)s2 * 12 + sub];
        uint2 v3 = gp[(size_t)s3 * 12 + sub];
        a0 += bf2f((ushort)(v0.x & 0xffff)) + bf2f((ushort)(v1.x & 0xffff))
            + bf2f((ushort)(v2.x & 0xffff)) + bf2f((ushort)(v3.x & 0xffff));
        a1 += bf2f((ushort)(v0.x >> 16)) + bf2f((ushort)(v1.x >> 16))
            + bf2f((ushort)(v2.x >> 16)) + bf2f((ushort)(v3.x >> 16));
        a2 += bf2f((ushort)(v0.y & 0xffff)) + bf2f((ushort)(v1.y & 0xffff))
            + bf2f((ushort)(v2.y & 0xffff)) + bf2f((ushort)(v3.y & 0xffff));
        a3 += bf2f((ushort)(v0.y >> 16)) + bf2f((ushort)(v1.y >> 16))
            + bf2f((ushort)(v2.y >> 16)) + bf2f((ushort)(v3.y >> 16));
    }
    for (; e < end; ++e) {
        int s = sorted_src[e];
        uint2 v = gp[(size_t)s * 12 + sub];
        a0 += bf2f((ushort)(v.x & 0xffff));
        a1 += bf2f((ushort)(v.x >> 16));
        a2 += bf2f((ushort)(v.y & 0xffff));
        a3 += bf2f((ushort)(v.y >> 16));
    }
    float di = rsqrtf((float)cnt + 1.0f);
    float4 r;
    r.x = a0 * di; r.y = a1 * di; r.z = a2 * di; r.w = a3 * di;
    ((float4*)out)[(size_t)node * 12 + sub] = r;
}

// ---------------------------------------------------------------------------
// k_stats: per-channel sum and sum-of-squares of out (256 blocks only)
// ---------------------------------------------------------------------------
__global__ __launch_bounds__(768) void k_stats(const float* __restrict__ v,
                                               float* __restrict__ stats, int N) {
    __shared__ float ls[16][OUT_CH];
    __shared__ float ls2[16][OUT_CH];
    int c = threadIdx.x;   // 0..47
    int ty = threadIdx.y;  // 0..15
    float s = 0.f, s2 = 0.f;
    for (int r = blockIdx.x * 16 + ty; r < N; r += gridDim.x * 16) {
        float u = v[(size_t)r * OUT_CH + c];
        s += u;
        s2 += u * u;
    }
    ls[ty][c] = s;
    ls2[ty][c] = s2;
    __syncthreads();
    for (int h = 8; h > 0; h >>= 1) {
        if (ty < h) {
            ls[ty][c] += ls[ty + h][c];
            ls2[ty][c] += ls2[ty + h][c];
        }
        __syncthreads();
    }
    if (ty == 0) {
        atomicAdd(&stats[c], ls[0][c]);
        atomicAdd(&stats[OUT_CH + c], ls2[0][c]);
    }
}

// ---------------------------------------------------------------------------
// k_final: BN (batch stats) + ReLU, in place. GCN bias b cancels under BN.
// ---------------------------------------------------------------------------
__global__ void k_final(float* __restrict__ out, const float* __restrict__ stats,
                        const float* __restrict__ gamma,
                        const float* __restrict__ beta, int N) {
    int t = blockIdx.x * blockDim.x + threadIdx.x;
    int total = N * OUT_CH;
    if (t >= total) return;
    int c = t % OUT_CH;
    float invN = 1.0f / (float)N;
    float m = stats[c] * invN;
    float var = stats[OUT_CH + c] * invN - m * m;
    float y = (out[t] - m) * rsqrtf(var + BN_EPS) * gamma[c] + beta[c];
    out[t] = fmaxf(y, 0.0f);
}

extern "C" void kernel_launch(void* const* d_in, const int* in_sizes, int n_in,
                              void* d_out, int out_size, void* d_ws, size_t ws_size,
                              hipStream_t stream) {
    const float* x     = (const float*)d_in[0];
    const int*   ei    = (const int*)d_in[1];
    const float* W     = (const float*)d_in[2];
    // d_in[3] = b : constant per-channel offset cancels in BatchNorm -> unused
    const float* gamma = (const float*)d_in[4];
    const float* beta  = (const float*)d_in[5];
    float*       out   = (float*)d_out;

    int N = in_sizes[0] / IN_CH;     // 100000 (< 2^17 for packing)
    int E = in_sizes[1] / 2;         // 1600000
    const int* src = ei;             // edge_index[0]
    const int* dst = ei + E;         // edge_index[1]

    int nb = (N + NPB - 1) / NPB;    // 391 buckets

    // workspace layout (bytes):
    // [0, 512)          stats float[128]
    // [512, 2564)       bstart int[513]
    // [4096, 6144)      bcur int[512]
    // [8192, 10240)     bhist int[512]
    // [139264=A, +4N)   counts int[N]
    // [.., +4N)         rowstart int[N]
    // [.., +4E)         binned uint[E]
    // [.., +4E)         sorted_src int[E]
    // [.., +96N)        g bf16[N*48] (16B aligned)
    char* wsb = (char*)d_ws;
    float*        stats      = (float*)wsb;
    int*          bstart     = (int*)(wsb + 512);
    int*          bcur       = (int*)(wsb + 4096);
    int*          bhist      = (int*)(wsb + 8192);
    size_t A = 139264;
    int*          counts     = (int*)(wsb + A);
    int*          rowstart   = (int*)(wsb + A + (size_t)4 * N);
    unsigned int* binned     = (unsigned int*)(wsb + A + (size_t)8 * N);
    int*          sorted_src = (int*)(wsb + A + (size_t)8 * N + (size_t)4 * E);
    ushort*       g          = (ushort*)(wsb + A + (size_t)8 * N + (size_t)8 * E);

    int b = 256;
    int nchunks = (E + CHUNK - 1) / CHUNK;   // 391
    int ngemm = (N + b - 1) / b;             // 391

    // 1. zero bhist
    k_zero<<<1, 512, 0, stream>>>(bhist);
    // 2. bucket histogram (512 blocks, LDS hist, atomic flush)
    k_binhist<<<NHB, b, 0, stream>>>(dst, bhist, E);
    // 3. scan -> bstart / bcur; zero stats
    k_scanb<<<1, b, 0, stream>>>(bhist, bstart, bcur, nb, stats);
    // 4. fused: coarse counting-sort (blocks 0..nchunks) + unscaled GEMM (rest)
    k_binmm<<<nchunks + ngemm, b, 0, stream>>>(src, dst, bcur, binned, E, nchunks,
                                               x, W, g, N);
    // 5. fine sort within buckets -> counts/rowstart/sorted_src + g rescale
    k_fine<<<nb, 512, 0, stream>>>(binned, bstart, counts, rowstart, sorted_src, g, N);
    // 6. gather + self loop + dst dinv (4 channels per thread, unroll-8)
    int gthreads = N * 12;
    k_gather<<<(gthreads + b - 1) / b, b, 0, stream>>>(sorted_src, rowstart, counts, g, out, N);
    // 7. BN stats
    dim3 sblk(OUT_CH, 16);
    k_stats<<<256, sblk, 0, stream>>>(out, stats, N);
    // 8. BN + ReLU in place
    int totalT = N * OUT_CH;
    k_final<<<(totalT + b - 1) / b, b, 0, stream>>>(out, stats, gamma, beta, N);
}